// Round 2
// baseline (665.441 us; speedup 1.0000x reference)
//
#include <hip/hip_runtime.h>
#include <hip/hip_bf16.h>
#include <cstdint>

#define NSTR 4
#define CH 2048
#define NCF 8192          // NSTR * CH
#define NJ 24             // 4 pre + 4 post + 16 res
#define EPS_F 1e-5f
#define SINK_ITERS 20

// ---------------------------------------------------------------------------
// Prep: phiW[j][k] = bf16( alpha_j * w[k % CH] * phi_j[k] ),  j in [0,24)
// j 0..3 -> phi_pre rows, 4..7 -> phi_post rows, 8..23 -> phi_res rows
// ---------------------------------------------------------------------------
__global__ void __launch_bounds__(256) prep_phi_kernel(
    const float* __restrict__ w,
    const float* __restrict__ phi_pre,
    const float* __restrict__ phi_post,
    const float* __restrict__ phi_res,
    const float* __restrict__ alpha_pre,
    const float* __restrict__ alpha_post,
    const float* __restrict__ alpha_res,
    uint16_t* __restrict__ phiW)
{
    int idx = blockIdx.x * 256 + threadIdx.x;
    if (idx >= NJ * NCF) return;
    int j = idx / NCF;
    int k = idx - j * NCF;
    int c = k & (CH - 1);
    float v, a;
    if (j < 4)      { v = phi_pre[j * NCF + k];        a = alpha_pre[0]; }
    else if (j < 8) { v = phi_post[(j - 4) * NCF + k]; a = alpha_post[0]; }
    else            { v = phi_res[(j - 8) * NCF + k];  a = alpha_res[0]; }
    float f = v * a * w[c];
    // RNE f32 -> bf16
    uint32_t u = __float_as_uint(f);
    uint32_t r = (u + 0x7fffu + ((u >> 16) & 1u)) >> 16;
    phiW[idx] = (uint16_t)r;
}

// ---------------------------------------------------------------------------
// Main fused kernel: one 512-thread block (8 waves) handles 2 batch rows.
// Thread t owns float4 quads at flat k = 4t + 2048*jj, jj = 0..3.
// Since 4t < 2048, quad jj lives entirely in stream jj at channel c = 4t.
// ---------------------------------------------------------------------------
__global__ void __launch_bounds__(512, 4) mhc_main_kernel(
    const float* __restrict__ x,
    const uint16_t* __restrict__ phiW,
    const float* __restrict__ b_pre,
    const float* __restrict__ b_post,
    const float* __restrict__ b_res,
    float* __restrict__ out)
{
    const int t = threadIdx.x;
    const int lane = t & 63;
    const int wave = t >> 6;              // 0..7
    const long b0 = (long)blockIdx.x * 2;

    __shared__ float red[8][8];
    __shared__ float hred[8][48];
    __shared__ float H[2][24];

    // ---- load both x rows into registers (coalesced float4) ----
    // xv[r][jj] = x[row r][stream jj][c = 4t .. 4t+3]
    float4 xv[2][4];
    const float4* xp0 = reinterpret_cast<const float4*>(x + b0 * NCF);
    const float4* xp1 = reinterpret_cast<const float4*>(x + (b0 + 1) * NCF);
    #pragma unroll
    for (int jj = 0; jj < 4; ++jj) {
        xv[0][jj] = xp0[t + 512 * jj];
        xv[1][jj] = xp1[t + 512 * jj];
    }

    // ---- RMS: sum of squares per (row, stream), block reduce ----
    float scl[2][4];
    {
        float ssp[8];
        #pragma unroll
        for (int r = 0; r < 2; ++r) {
            #pragma unroll
            for (int s = 0; s < 4; ++s) {
                float4 a = xv[r][s];
                ssp[r * 4 + s] = a.x * a.x + a.y * a.y + a.z * a.z + a.w * a.w;
            }
        }
        #pragma unroll
        for (int i = 0; i < 8; ++i) {
            float v = ssp[i];
            #pragma unroll
            for (int m = 1; m < 64; m <<= 1) v += __shfl_xor(v, m, 64);
            if (lane == 0) red[wave][i] = v;
        }
        __syncthreads();
        #pragma unroll
        for (int i = 0; i < 8; ++i) {
            float ss = red[0][i] + red[1][i] + red[2][i] + red[3][i]
                     + red[4][i] + red[5][i] + red[6][i] + red[7][i];
            scl[i >> 2][i & 3] = rsqrtf(ss * (1.0f / CH) + EPS_F);
        }
    }

    // ---- 24 projection dots, phi streamed as bf16, both rows per load ----
    float acc[2][NJ];
    #pragma unroll
    for (int j = 0; j < NJ; ++j) { acc[0][j] = 0.0f; acc[1][j] = 0.0f; }

    const uint2* pp = reinterpret_cast<const uint2*>(phiW);  // 4 bf16 per uint2
    #pragma unroll
    for (int jj = 0; jj < 4; ++jj) {
        const int qidx = t + 512 * jj;    // uint2 index within a phi row
        const float sA = scl[0][jj];
        const float sB = scl[1][jj];
        const float x0 = xv[0][jj].x * sA, x1 = xv[0][jj].y * sA,
                    x2 = xv[0][jj].z * sA, x3 = xv[0][jj].w * sA;
        const float y0 = xv[1][jj].x * sB, y1 = xv[1][jj].y * sB,
                    y2 = xv[1][jj].z * sB, y3 = xv[1][jj].w * sB;
        #pragma unroll
        for (int j = 0; j < NJ; ++j) {
            uint2 pv = pp[j * (NCF / 4) + qidx];
            float p0 = __uint_as_float(pv.x << 16);
            float p1 = __uint_as_float(pv.x & 0xffff0000u);
            float p2 = __uint_as_float(pv.y << 16);
            float p3 = __uint_as_float(pv.y & 0xffff0000u);
            acc[0][j] = fmaf(x3, p3, fmaf(x2, p2, fmaf(x1, p1, fmaf(x0, p0, acc[0][j]))));
            acc[1][j] = fmaf(y3, p3, fmaf(y2, p2, fmaf(y1, p1, fmaf(y0, p0, acc[1][j]))));
        }
    }

    // ---- reduce 48 partial dots across the block ----
    #pragma unroll
    for (int j = 0; j < NJ; ++j) {
        float v0 = acc[0][j], v1 = acc[1][j];
        #pragma unroll
        for (int m = 1; m < 64; m <<= 1) {
            v0 += __shfl_xor(v0, m, 64);
            v1 += __shfl_xor(v1, m, 64);
        }
        if (lane == 0) { hred[wave][j] = v0; hred[wave][24 + j] = v1; }
    }
    __syncthreads();

    // ---- finalize h (add biases) ----
    if (t < 48) {
        int r = (t >= 24) ? 1 : 0;
        int j = t - 24 * r;
        float v = 0.0f;
        #pragma unroll
        for (int w8 = 0; w8 < 8; ++w8) v += hred[w8][t];
        float bias;
        if (j < 4)      bias = b_pre[j];
        else if (j < 8) bias = b_post[j - 4];
        else            bias = b_res[j - 8];
        H[r][j] = v + bias;
    }
    __syncthreads();

    // ---- Sinkhorn on 4x4 logits, 16 lanes per row (lanes 0..31) ----
    if (t < 32) {
        int r = t >> 4;
        int q = t & 15;          // q = i*4 + jx
        float L = H[r][8 + q];
        float mx = L;
        mx = fmaxf(mx, __shfl_xor(mx, 1, 64));
        mx = fmaxf(mx, __shfl_xor(mx, 2, 64));
        mx = fmaxf(mx, __shfl_xor(mx, 4, 64));
        mx = fmaxf(mx, __shfl_xor(mx, 8, 64));
        float m = __expf(L - mx);
        #pragma unroll
        for (int it = 0; it < SINK_ITERS; ++it) {
            float rs = m + __shfl_xor(m, 1, 64);
            rs += __shfl_xor(rs, 2, 64);
            m = m / (rs + EPS_F);           // row normalize (sum over jx)
            float cs = m + __shfl_xor(m, 4, 64);
            cs += __shfl_xor(cs, 8, 64);
            m = m / (cs + EPS_F);           // col normalize (sum over i)
        }
        H[r][8 + q] = m;
    }
    __syncthreads();

    // ---- mixing epilogue: out[i][c] = sum_j hres[i][j]*x[j][c] + hq[i]*agg[c]
    #pragma unroll
    for (int r = 0; r < 2; ++r) {
        float hp[4], hq[4], hrm[4][4];
        #pragma unroll
        for (int i = 0; i < 4; ++i) {
            hp[i] = H[r][i];
            hq[i] = H[r][4 + i];
            #pragma unroll
            for (int j = 0; j < 4; ++j) hrm[i][j] = H[r][8 + 4 * i + j];
        }
        float4* op = reinterpret_cast<float4*>(out + (b0 + r) * NCF);
        float4 s0 = xv[r][0], s1 = xv[r][1], s2 = xv[r][2], s3 = xv[r][3];
        float ax = hp[0] * s0.x + hp[1] * s1.x + hp[2] * s2.x + hp[3] * s3.x;
        float ay = hp[0] * s0.y + hp[1] * s1.y + hp[2] * s2.y + hp[3] * s3.y;
        float az = hp[0] * s0.z + hp[1] * s1.z + hp[2] * s2.z + hp[3] * s3.z;
        float aw = hp[0] * s0.w + hp[1] * s1.w + hp[2] * s2.w + hp[3] * s3.w;
        #pragma unroll
        for (int i = 0; i < 4; ++i) {
            float4 o;
            o.x = hrm[i][0] * s0.x + hrm[i][1] * s1.x + hrm[i][2] * s2.x + hrm[i][3] * s3.x + hq[i] * ax;
            o.y = hrm[i][0] * s0.y + hrm[i][1] * s1.y + hrm[i][2] * s2.y + hrm[i][3] * s3.y + hq[i] * ay;
            o.z = hrm[i][0] * s0.z + hrm[i][1] * s1.z + hrm[i][2] * s2.z + hrm[i][3] * s3.z + hq[i] * az;
            o.w = hrm[i][0] * s0.w + hrm[i][1] * s1.w + hrm[i][2] * s2.w + hrm[i][3] * s3.w + hq[i] * aw;
            op[i * 512 + t] = o;
        }
    }
}

extern "C" void kernel_launch(void* const* d_in, const int* in_sizes, int n_in,
                              void* d_out, int out_size, void* d_ws, size_t ws_size,
                              hipStream_t stream)
{
    const float* x        = (const float*)d_in[0];
    const float* w        = (const float*)d_in[1];
    const float* phi_pre  = (const float*)d_in[2];
    const float* phi_post = (const float*)d_in[3];
    const float* phi_res  = (const float*)d_in[4];
    const float* b_pre    = (const float*)d_in[5];
    const float* b_post   = (const float*)d_in[6];
    const float* b_res    = (const float*)d_in[7];
    const float* a_pre    = (const float*)d_in[8];
    const float* a_post   = (const float*)d_in[9];
    const float* a_res    = (const float*)d_in[10];
    float* out = (float*)d_out;
    uint16_t* phiW = (uint16_t*)d_ws;   // NJ * NCF * 2 bytes = 384 KiB

    const int B = in_sizes[0] / NCF;    // 8192

    prep_phi_kernel<<<(NJ * NCF + 255) / 256, 256, 0, stream>>>(
        w, phi_pre, phi_post, phi_res, a_pre, a_post, a_res, phiW);

    mhc_main_kernel<<<B / 2, 512, 0, stream>>>(
        x, phiW, b_pre, b_post, b_res, out);
}

// Round 3
// 243.431 us; speedup vs baseline: 2.7336x; 2.7336x over previous
//
#include <hip/hip_runtime.h>
#include <hip/hip_bf16.h>
#include <cstdint>

#define CH 2048
#define NCF 8192          // 4 * CH
#define NJ 24             // 4 pre + 4 post + 16 res
#define EPS_F 1e-5f
#define SINK_ITERS 20

// ---------------------------------------------------------------------------
// Prep: phiW[j][k] = bf16( alpha_j * w[k % CH] * phi_j[k] ),  j in [0,24)
// ---------------------------------------------------------------------------
__global__ void __launch_bounds__(256) prep_phi_kernel(
    const float* __restrict__ w,
    const float* __restrict__ phi_pre,
    const float* __restrict__ phi_post,
    const float* __restrict__ phi_res,
    const float* __restrict__ alpha_pre,
    const float* __restrict__ alpha_post,
    const float* __restrict__ alpha_res,
    uint16_t* __restrict__ phiW)
{
    int idx = blockIdx.x * 256 + threadIdx.x;
    if (idx >= NJ * NCF) return;
    int j = idx / NCF;
    int k = idx - j * NCF;
    int c = k & (CH - 1);
    float v, a;
    if (j < 4)      { v = phi_pre[j * NCF + k];        a = alpha_pre[0]; }
    else if (j < 8) { v = phi_post[(j - 4) * NCF + k]; a = alpha_post[0]; }
    else            { v = phi_res[(j - 8) * NCF + k];  a = alpha_res[0]; }
    float f = v * a * w[c];
    uint32_t u = __float_as_uint(f);
    uint32_t r = (u + 0x7fffu + ((u >> 16) & 1u)) >> 16;   // RNE f32->bf16
    phiW[idx] = (uint16_t)r;
}

// ---------------------------------------------------------------------------
// Main fused kernel: 512 threads (8 waves) per block, 2 batch rows per block.
// Raw x staged in LDS (64 KiB). Wave w owns projection rows j = 3w..3w+2;
// RMS scale folded in per-stream at segment boundaries so LDS x stays raw.
// ---------------------------------------------------------------------------
__global__ void __launch_bounds__(512) mhc_main_kernel(
    const float* __restrict__ x,
    const uint16_t* __restrict__ phiW,
    const float* __restrict__ b_pre,
    const float* __restrict__ b_post,
    const float* __restrict__ b_res,
    float* __restrict__ out)
{
    const int t = threadIdx.x;
    const int lane = t & 63;
    const int wave = t >> 6;              // 0..7
    const long b0 = (long)blockIdx.x * 2;

    __shared__ float xs[2 * NCF];         // raw x, 64 KiB
    __shared__ float red[8][8];
    __shared__ float SCL[2][4];
    __shared__ float hred[8][6];
    __shared__ float H[2][24];

    // ---- Phase A: global -> LDS, accumulate sum-of-squares per (row,stream)
    {
        const float4* xp0 = reinterpret_cast<const float4*>(x + b0 * NCF);
        const float4* xp1 = reinterpret_cast<const float4*>(x + (b0 + 1) * NCF);
        float4* xs4 = reinterpret_cast<float4*>(xs);
        float ssp[8];
        #pragma unroll
        for (int jj = 0; jj < 4; ++jj) {   // quad jj = stream jj (4t < 2048)
            float4 a = xp0[t + 512 * jj];
            float4 b = xp1[t + 512 * jj];
            xs4[t + 512 * jj] = a;
            xs4[2048 + t + 512 * jj] = b;
            ssp[jj]     = a.x * a.x + a.y * a.y + a.z * a.z + a.w * a.w;
            ssp[4 + jj] = b.x * b.x + b.y * b.y + b.z * b.z + b.w * b.w;
        }
        #pragma unroll
        for (int i = 0; i < 8; ++i) {
            float v = ssp[i];
            #pragma unroll
            for (int m = 1; m < 64; m <<= 1) v += __shfl_xor(v, m, 64);
            if (lane == 0) red[wave][i] = v;
        }
    }
    __syncthreads();
    if (t < 8) {                            // t = row*4 + stream
        float ss = 0.0f;
        #pragma unroll
        for (int w8 = 0; w8 < 8; ++w8) ss += red[w8][t];
        SCL[t >> 2][t & 3] = rsqrtf(ss * (1.0f / CH) + EPS_F);
    }
    __syncthreads();

    // ---- Phase B: wave w computes dots for j = 3w..3w+2, both rows ----
    const int jbase = wave * 3;
    float accT[2][3] = {{0.f, 0.f, 0.f}, {0.f, 0.f, 0.f}};
    const uint2* pp = reinterpret_cast<const uint2*>(phiW) + (size_t)jbase * (NCF / 4);
    for (int s = 0; s < 4; ++s) {          // stream segments
        float accS[2][3] = {{0.f, 0.f, 0.f}, {0.f, 0.f, 0.f}};
        #pragma unroll
        for (int ii = 0; ii < 8; ++ii) {
            const int k = 2048 * s + 256 * ii + 4 * lane;
            const float4 xa = *reinterpret_cast<const float4*>(xs + k);
            const float4 xb = *reinterpret_cast<const float4*>(xs + NCF + k);
            #pragma unroll
            for (int jl = 0; jl < 3; ++jl) {
                uint2 pv = pp[jl * (NCF / 4) + (k >> 2)];
                float p0 = __uint_as_float(pv.x << 16);
                float p1 = __uint_as_float(pv.x & 0xffff0000u);
                float p2 = __uint_as_float(pv.y << 16);
                float p3 = __uint_as_float(pv.y & 0xffff0000u);
                accS[0][jl] = fmaf(xa.w, p3, fmaf(xa.z, p2, fmaf(xa.y, p1, fmaf(xa.x, p0, accS[0][jl]))));
                accS[1][jl] = fmaf(xb.w, p3, fmaf(xb.z, p2, fmaf(xb.y, p1, fmaf(xb.x, p0, accS[1][jl]))));
            }
        }
        const float sA = SCL[0][s], sB = SCL[1][s];
        #pragma unroll
        for (int jl = 0; jl < 3; ++jl) {
            accT[0][jl] = fmaf(sA, accS[0][jl], accT[0][jl]);
            accT[1][jl] = fmaf(sB, accS[1][jl], accT[1][jl]);
        }
    }
    #pragma unroll
    for (int r = 0; r < 2; ++r) {
        #pragma unroll
        for (int jl = 0; jl < 3; ++jl) {
            float v = accT[r][jl];
            #pragma unroll
            for (int m = 1; m < 64; m <<= 1) v += __shfl_xor(v, m, 64);
            if (lane == 0) hred[wave][r * 3 + jl] = v;
        }
    }
    __syncthreads();

    // ---- finalize h (gather + biases) ----
    if (t < 48) {
        const int r = (t >= 24) ? 1 : 0;
        const int j = t - 24 * r;
        float v = hred[j / 3][r * 3 + (j % 3)];
        float bias;
        if (j < 4)      bias = b_pre[j];
        else if (j < 8) bias = b_post[j - 4];
        else            bias = b_res[j - 8];
        H[r][j] = v + bias;
    }
    __syncthreads();

    // ---- Sinkhorn on 4x4 logits, 16 lanes per row (lanes 0..31) ----
    if (t < 32) {
        int r = t >> 4;
        int q = t & 15;          // q = i*4 + jx
        float L = H[r][8 + q];
        float mx = L;
        mx = fmaxf(mx, __shfl_xor(mx, 1, 64));
        mx = fmaxf(mx, __shfl_xor(mx, 2, 64));
        mx = fmaxf(mx, __shfl_xor(mx, 4, 64));
        mx = fmaxf(mx, __shfl_xor(mx, 8, 64));
        float m = __expf(L - mx);
        #pragma unroll
        for (int it = 0; it < SINK_ITERS; ++it) {
            float rs = m + __shfl_xor(m, 1, 64);
            rs += __shfl_xor(rs, 2, 64);
            m = m / (rs + EPS_F);           // row normalize (sum over jx)
            float cs = m + __shfl_xor(m, 4, 64);
            cs += __shfl_xor(cs, 8, 64);
            m = m / (cs + EPS_F);           // col normalize (sum over i)
        }
        H[r][8 + q] = m;
    }
    __syncthreads();

    // ---- Phase D: mixing epilogue from LDS x (raw) ----
    #pragma unroll
    for (int r = 0; r < 2; ++r) {
        float hp[4], hq[4], hrm[4][4];
        #pragma unroll
        for (int i = 0; i < 4; ++i) {
            hp[i] = H[r][i];
            hq[i] = H[r][4 + i];
            #pragma unroll
            for (int j = 0; j < 4; ++j) hrm[i][j] = H[r][8 + 4 * i + j];
        }
        const float* xr = xs + r * NCF + 4 * t;
        float4 s0 = *reinterpret_cast<const float4*>(xr);
        float4 s1 = *reinterpret_cast<const float4*>(xr + 2048);
        float4 s2 = *reinterpret_cast<const float4*>(xr + 4096);
        float4 s3 = *reinterpret_cast<const float4*>(xr + 6144);
        float ax = hp[0] * s0.x + hp[1] * s1.x + hp[2] * s2.x + hp[3] * s3.x;
        float ay = hp[0] * s0.y + hp[1] * s1.y + hp[2] * s2.y + hp[3] * s3.y;
        float az = hp[0] * s0.z + hp[1] * s1.z + hp[2] * s2.z + hp[3] * s3.z;
        float aw = hp[0] * s0.w + hp[1] * s1.w + hp[2] * s2.w + hp[3] * s3.w;
        float4* op = reinterpret_cast<float4*>(out + (b0 + r) * NCF + 4 * t);
        #pragma unroll
        for (int i = 0; i < 4; ++i) {
            float4 o;
            o.x = hrm[i][0] * s0.x + hrm[i][1] * s1.x + hrm[i][2] * s2.x + hrm[i][3] * s3.x + hq[i] * ax;
            o.y = hrm[i][0] * s0.y + hrm[i][1] * s1.y + hrm[i][2] * s2.y + hrm[i][3] * s3.y + hq[i] * ay;
            o.z = hrm[i][0] * s0.z + hrm[i][1] * s1.z + hrm[i][2] * s2.z + hrm[i][3] * s3.z + hq[i] * az;
            o.w = hrm[i][0] * s0.w + hrm[i][1] * s1.w + hrm[i][2] * s2.w + hrm[i][3] * s3.w + hq[i] * aw;
            op[i * 512] = o;
        }
    }
}

extern "C" void kernel_launch(void* const* d_in, const int* in_sizes, int n_in,
                              void* d_out, int out_size, void* d_ws, size_t ws_size,
                              hipStream_t stream)
{
    const float* x        = (const float*)d_in[0];
    const float* w        = (const float*)d_in[1];
    const float* phi_pre  = (const float*)d_in[2];
    const float* phi_post = (const float*)d_in[3];
    const float* phi_res  = (const float*)d_in[4];
    const float* b_pre    = (const float*)d_in[5];
    const float* b_post   = (const float*)d_in[6];
    const float* b_res    = (const float*)d_in[7];
    const float* a_pre    = (const float*)d_in[8];
    const float* a_post   = (const float*)d_in[9];
    const float* a_res    = (const float*)d_in[10];
    float* out = (float*)d_out;
    uint16_t* phiW = (uint16_t*)d_ws;   // NJ * NCF * 2 bytes = 384 KiB

    const int B = in_sizes[0] / NCF;    // 8192

    prep_phi_kernel<<<(NJ * NCF + 255) / 256, 256, 0, stream>>>(
        w, phi_pre, phi_post, phi_res, a_pre, a_post, a_res, phiW);

    mhc_main_kernel<<<B / 2, 512, 0, stream>>>(
        x, phiW, b_pre, b_post, b_res, out);
}

// Round 5
// 240.543 us; speedup vs baseline: 2.7664x; 1.0120x over previous
//
#include <hip/hip_runtime.h>
#include <hip/hip_bf16.h>
#include <cstdint>

#define CH 2048
#define NCF 8192          // 4 * CH
#define NJ 24             // 4 pre + 4 post + 16 res
#define EPS_F 1e-5f
#define SINK_ITERS 20

typedef float v4f __attribute__((ext_vector_type(4)));

// ---------------------------------------------------------------------------
// Prep: phiW[j][k] = bf16( alpha_j * w[k % CH] * phi_j[k] ),  j in [0,24)
// ---------------------------------------------------------------------------
__global__ void __launch_bounds__(256) prep_phi_kernel(
    const float* __restrict__ w,
    const float* __restrict__ phi_pre,
    const float* __restrict__ phi_post,
    const float* __restrict__ phi_res,
    const float* __restrict__ alpha_pre,
    const float* __restrict__ alpha_post,
    const float* __restrict__ alpha_res,
    uint16_t* __restrict__ phiW)
{
    int idx = blockIdx.x * 256 + threadIdx.x;
    if (idx >= NJ * NCF) return;
    int j = idx / NCF;
    int k = idx - j * NCF;
    int c = k & (CH - 1);
    float v, a;
    if (j < 4)      { v = phi_pre[j * NCF + k];        a = alpha_pre[0]; }
    else if (j < 8) { v = phi_post[(j - 4) * NCF + k]; a = alpha_post[0]; }
    else            { v = phi_res[(j - 8) * NCF + k];  a = alpha_res[0]; }
    float f = v * a * w[c];
    uint32_t u = __float_as_uint(f);
    uint32_t r = (u + 0x7fffu + ((u >> 16) & 1u)) >> 16;   // RNE f32->bf16
    phiW[idx] = (uint16_t)r;
}

// ---------------------------------------------------------------------------
// Main fused kernel: 512 threads (8 waves), ONE batch row per block.
// Raw f32 x staged in LDS (32 KiB) -> 4 blocks/CU, 32 waves/CU.
// Wave w owns projection rows j = 3w..3w+2; RMS scale folded in per-stream
// at segment boundaries so LDS x stays raw (exact f32 mixing epilogue).
// ---------------------------------------------------------------------------
__global__ void __launch_bounds__(512, 4) mhc_main_kernel(
    const float* __restrict__ x,
    const uint16_t* __restrict__ phiW,
    const float* __restrict__ b_pre,
    const float* __restrict__ b_post,
    const float* __restrict__ b_res,
    float* __restrict__ out)
{
    const int t = threadIdx.x;
    const int lane = t & 63;
    const int wave = t >> 6;              // 0..7
    const long b = blockIdx.x;

    __shared__ float xs[NCF];             // raw x row, 32 KiB
    __shared__ float red[8][4];
    __shared__ float SCL[4];
    __shared__ float hred[8][3];
    __shared__ float H[24];

    // ---- Phase A: global -> LDS, sum-of-squares per stream ----
    {
        const float4* xp = reinterpret_cast<const float4*>(x + b * NCF);
        float4* xs4 = reinterpret_cast<float4*>(xs);
        float ssp[4];
        #pragma unroll
        for (int jj = 0; jj < 4; ++jj) {   // float4 quad jj lies in stream jj
            float4 a = xp[t + 512 * jj];
            xs4[t + 512 * jj] = a;
            ssp[jj] = a.x * a.x + a.y * a.y + a.z * a.z + a.w * a.w;
        }
        #pragma unroll
        for (int i = 0; i < 4; ++i) {
            float v = ssp[i];
            #pragma unroll
            for (int m = 1; m < 64; m <<= 1) v += __shfl_xor(v, m, 64);
            if (lane == 0) red[wave][i] = v;
        }
    }
    __syncthreads();
    if (t < 4) {
        float ss = 0.0f;
        #pragma unroll
        for (int w8 = 0; w8 < 8; ++w8) ss += red[w8][t];
        SCL[t] = rsqrtf(ss * (1.0f / CH) + EPS_F);
    }
    __syncthreads();

    // ---- Phase B: wave w computes dots for j = 3w..3w+2 ----
    const int jbase = wave * 3;
    float accT[3] = {0.f, 0.f, 0.f};
    const uint2* pp = reinterpret_cast<const uint2*>(phiW) + (size_t)jbase * (NCF / 4);
    for (int s = 0; s < 4; ++s) {          // stream segments
        float accS[3] = {0.f, 0.f, 0.f};
        #pragma unroll
        for (int ii = 0; ii < 8; ++ii) {
            const int k = 2048 * s + 256 * ii + 4 * lane;
            const float4 xa = *reinterpret_cast<const float4*>(xs + k);
            #pragma unroll
            for (int jl = 0; jl < 3; ++jl) {
                uint2 pv = pp[jl * (NCF / 4) + (k >> 2)];
                float p0 = __uint_as_float(pv.x << 16);
                float p1 = __uint_as_float(pv.x & 0xffff0000u);
                float p2 = __uint_as_float(pv.y << 16);
                float p3 = __uint_as_float(pv.y & 0xffff0000u);
                accS[jl] = fmaf(xa.w, p3, fmaf(xa.z, p2, fmaf(xa.y, p1, fmaf(xa.x, p0, accS[jl]))));
            }
        }
        const float sA = SCL[s];
        #pragma unroll
        for (int jl = 0; jl < 3; ++jl) accT[jl] = fmaf(sA, accS[jl], accT[jl]);
    }
    #pragma unroll
    for (int jl = 0; jl < 3; ++jl) {
        float v = accT[jl];
        #pragma unroll
        for (int m = 1; m < 64; m <<= 1) v += __shfl_xor(v, m, 64);
        if (lane == 0) hred[wave][jl] = v;
    }
    __syncthreads();

    // ---- finalize h (gather + biases) ----
    if (t < 24) {
        float v = hred[t / 3][t % 3];
        float bias;
        if (t < 4)      bias = b_pre[t];
        else if (t < 8) bias = b_post[t - 4];
        else            bias = b_res[t - 8];
        H[t] = v + bias;
    }
    __syncthreads();

    // ---- Sinkhorn on 4x4 logits, lanes 0..15 ----
    if (t < 16) {
        const int q = t;          // q = i*4 + jx
        float L = H[8 + q];
        float mx = L;
        mx = fmaxf(mx, __shfl_xor(mx, 1, 64));
        mx = fmaxf(mx, __shfl_xor(mx, 2, 64));
        mx = fmaxf(mx, __shfl_xor(mx, 4, 64));
        mx = fmaxf(mx, __shfl_xor(mx, 8, 64));
        float m = __expf(L - mx);
        #pragma unroll
        for (int it = 0; it < SINK_ITERS; ++it) {
            float rs = m + __shfl_xor(m, 1, 64);
            rs += __shfl_xor(rs, 2, 64);
            m = m / (rs + EPS_F);           // row normalize (sum over jx)
            float cs = m + __shfl_xor(m, 4, 64);
            cs += __shfl_xor(cs, 8, 64);
            m = m / (cs + EPS_F);           // col normalize (sum over i)
        }
        H[8 + q] = m;
    }
    __syncthreads();

    // ---- Phase D: mixing epilogue from LDS x (raw f32, exact) ----
    {
        float hp[4], hq[4], hrm[4][4];
        #pragma unroll
        for (int i = 0; i < 4; ++i) {
            hp[i] = H[i];
            hq[i] = H[4 + i];
            #pragma unroll
            for (int j = 0; j < 4; ++j) hrm[i][j] = H[8 + 4 * i + j];
        }
        const float* xr = xs + 4 * t;
        float4 s0 = *reinterpret_cast<const float4*>(xr);
        float4 s1 = *reinterpret_cast<const float4*>(xr + 2048);
        float4 s2 = *reinterpret_cast<const float4*>(xr + 4096);
        float4 s3 = *reinterpret_cast<const float4*>(xr + 6144);
        float ax = hp[0] * s0.x + hp[1] * s1.x + hp[2] * s2.x + hp[3] * s3.x;
        float ay = hp[0] * s0.y + hp[1] * s1.y + hp[2] * s2.y + hp[3] * s3.y;
        float az = hp[0] * s0.z + hp[1] * s1.z + hp[2] * s2.z + hp[3] * s3.z;
        float aw = hp[0] * s0.w + hp[1] * s1.w + hp[2] * s2.w + hp[3] * s3.w;
        v4f* op = reinterpret_cast<v4f*>(out + b * NCF + 4 * t);
        #pragma unroll
        for (int i = 0; i < 4; ++i) {
            v4f o;
            o.x = hrm[i][0] * s0.x + hrm[i][1] * s1.x + hrm[i][2] * s2.x + hrm[i][3] * s3.x + hq[i] * ax;
            o.y = hrm[i][0] * s0.y + hrm[i][1] * s1.y + hrm[i][2] * s2.y + hrm[i][3] * s3.y + hq[i] * ay;
            o.z = hrm[i][0] * s0.z + hrm[i][1] * s1.z + hrm[i][2] * s2.z + hrm[i][3] * s3.z + hq[i] * az;
            o.w = hrm[i][0] * s0.w + hrm[i][1] * s1.w + hrm[i][2] * s2.w + hrm[i][3] * s3.w + hq[i] * aw;
            __builtin_nontemporal_store(o, op + i * 512);
        }
    }
}

extern "C" void kernel_launch(void* const* d_in, const int* in_sizes, int n_in,
                              void* d_out, int out_size, void* d_ws, size_t ws_size,
                              hipStream_t stream)
{
    const float* x        = (const float*)d_in[0];
    const float* w        = (const float*)d_in[1];
    const float* phi_pre  = (const float*)d_in[2];
    const float* phi_post = (const float*)d_in[3];
    const float* phi_res  = (const float*)d_in[4];
    const float* b_pre    = (const float*)d_in[5];
    const float* b_post   = (const float*)d_in[6];
    const float* b_res    = (const float*)d_in[7];
    const float* a_pre    = (const float*)d_in[8];
    const float* a_post   = (const float*)d_in[9];
    const float* a_res    = (const float*)d_in[10];
    float* out = (float*)d_out;
    uint16_t* phiW = (uint16_t*)d_ws;   // NJ * NCF * 2 bytes = 384 KiB

    const int B = in_sizes[0] / NCF;    // 8192

    prep_phi_kernel<<<(NJ * NCF + 255) / 256, 256, 0, stream>>>(
        w, phi_pre, phi_post, phi_res, a_pre, a_post, a_res, phiW);

    mhc_main_kernel<<<B, 512, 0, stream>>>(
        x, phiW, b_pre, b_post, b_res, out);
}

// Round 6
// 200.630 us; speedup vs baseline: 3.3168x; 1.1989x over previous
//
#include <hip/hip_runtime.h>
#include <hip/hip_bf16.h>
#include <cstdint>

#define CH 2048
#define NCF 8192          // 4 * CH
#define NJ 24             // 4 pre + 4 post + 16 res
#define EPS_F 1e-5f
#define SINK_ITERS 20

typedef float v4f __attribute__((ext_vector_type(4)));

__device__ __forceinline__ uint32_t bf16rne(float f) {
    uint32_t u = __float_as_uint(f);
    return (u + 0x7fffu + ((u >> 16) & 1u)) >> 16;
}

// ---------------------------------------------------------------------------
// Prep: phiW[j][k] = bf16( alpha_j * w[k % CH] * phi_j[k] ),  j in [0,24)
// ---------------------------------------------------------------------------
__global__ void __launch_bounds__(256) prep_phi_kernel(
    const float* __restrict__ w,
    const float* __restrict__ phi_pre,
    const float* __restrict__ phi_post,
    const float* __restrict__ phi_res,
    const float* __restrict__ alpha_pre,
    const float* __restrict__ alpha_post,
    const float* __restrict__ alpha_res,
    uint16_t* __restrict__ phiW)
{
    int idx = blockIdx.x * 256 + threadIdx.x;
    if (idx >= NJ * NCF) return;
    int j = idx / NCF;
    int k = idx - j * NCF;
    int c = k & (CH - 1);
    float v, a;
    if (j < 4)      { v = phi_pre[j * NCF + k];        a = alpha_pre[0]; }
    else if (j < 8) { v = phi_post[(j - 4) * NCF + k]; a = alpha_post[0]; }
    else            { v = phi_res[(j - 8) * NCF + k];  a = alpha_res[0]; }
    phiW[idx] = (uint16_t)bf16rne(v * a * w[c]);
}

// unpack 8 packed bf16 (as uint4) into 8 f32
#define UNPACK8(v, f)                                   \
    f[0] = __uint_as_float((v).x << 16);                \
    f[1] = __uint_as_float((v).x & 0xffff0000u);        \
    f[2] = __uint_as_float((v).y << 16);                \
    f[3] = __uint_as_float((v).y & 0xffff0000u);        \
    f[4] = __uint_as_float((v).z << 16);                \
    f[5] = __uint_as_float((v).z & 0xffff0000u);        \
    f[6] = __uint_as_float((v).w << 16);                \
    f[7] = __uint_as_float((v).w & 0xffff0000u);

__device__ __forceinline__ void dot_step(
    const uint4& xw, const uint4& p0, const uint4& p1, const uint4& p2,
    float& a0, float& a1, float& a2)
{
    float xf[8], pf[8];
    UNPACK8(xw, xf);
    UNPACK8(p0, pf);
    #pragma unroll
    for (int e = 0; e < 8; ++e) a0 = fmaf(xf[e], pf[e], a0);
    UNPACK8(p1, pf);
    #pragma unroll
    for (int e = 0; e < 8; ++e) a1 = fmaf(xf[e], pf[e], a1);
    UNPACK8(p2, pf);
    #pragma unroll
    for (int e = 0; e < 8; ++e) a2 = fmaf(xf[e], pf[e], a2);
}

// ---------------------------------------------------------------------------
// Main fused kernel: 512 threads (8 waves), ONE batch row per block.
// x held in registers end-to-end; LDS holds pre-scaled bf16 xnorm (16 KiB).
// Wave w computes projection rows j = 3w..3w+2 with 2-stage ping-pong
// prefetch of phi (uint4) + xnorm (LDS uint4) to hide L2 latency.
// ---------------------------------------------------------------------------
__global__ void __launch_bounds__(512) mhc_main_kernel(
    const float* __restrict__ x,
    const uint16_t* __restrict__ phiW,
    const float* __restrict__ b_pre,
    const float* __restrict__ b_post,
    const float* __restrict__ b_res,
    float* __restrict__ out)
{
    const int t = threadIdx.x;
    const int lane = t & 63;
    const int wave = t >> 6;              // 0..7
    const long b = blockIdx.x;

    __shared__ uint32_t xn[NCF / 2];      // scaled bf16 xnorm, 16 KiB
    __shared__ float red[8][4];
    __shared__ float SCL[4];
    __shared__ float hred[8][3];
    __shared__ float H[24];

    // ---- Phase A: global -> registers, sum-of-squares per stream ----
    float4 xv[4];                          // raw x, quad jj = stream jj
    {
        const float4* xp = reinterpret_cast<const float4*>(x + b * NCF);
        float ssp[4];
        #pragma unroll
        for (int jj = 0; jj < 4; ++jj) {
            xv[jj] = xp[t + 512 * jj];
            ssp[jj] = xv[jj].x * xv[jj].x + xv[jj].y * xv[jj].y
                    + xv[jj].z * xv[jj].z + xv[jj].w * xv[jj].w;
        }
        #pragma unroll
        for (int i = 0; i < 4; ++i) {
            float v = ssp[i];
            #pragma unroll
            for (int m = 1; m < 64; m <<= 1) v += __shfl_xor(v, m, 64);
            if (lane == 0) red[wave][i] = v;
        }
    }
    __syncthreads();
    if (t < 4) {
        float ss = 0.0f;
        #pragma unroll
        for (int w8 = 0; w8 < 8; ++w8) ss += red[w8][t];
        SCL[t] = rsqrtf(ss * (1.0f / CH) + EPS_F);
    }
    __syncthreads();

    // ---- write scaled bf16 xnorm to LDS ----
    #pragma unroll
    for (int jj = 0; jj < 4; ++jj) {
        const float s = SCL[jj];
        uint32_t r0 = bf16rne(xv[jj].x * s);
        uint32_t r1 = bf16rne(xv[jj].y * s);
        uint32_t r2 = bf16rne(xv[jj].z * s);
        uint32_t r3 = bf16rne(xv[jj].w * s);
        uint2 pk = make_uint2(r0 | (r1 << 16), r2 | (r3 << 16));
        *reinterpret_cast<uint2*>(&xn[2 * t + 1024 * jj]) = pk;
    }
    __syncthreads();

    // ---- Phase B: wave w dots xnorm against phi rows 3w..3w+2 ----
    // 16 steps of 512 elems; lane covers 8 elems/step. 2-stage ping-pong.
    float a0 = 0.f, a1 = 0.f, a2 = 0.f;
    {
        const uint16_t* pw = phiW + (size_t)(wave * 3) * NCF;
        const int kl = 8 * lane;

        uint4 xwA = *reinterpret_cast<const uint4*>(&xn[kl >> 1]);
        uint4 pA0 = *reinterpret_cast<const uint4*>(pw + 0 * NCF + kl);
        uint4 pA1 = *reinterpret_cast<const uint4*>(pw + 1 * NCF + kl);
        uint4 pA2 = *reinterpret_cast<const uint4*>(pw + 2 * NCF + kl);

        #pragma unroll
        for (int u = 0; u < 16; u += 2) {
            // prefetch step u+1 into B
            const int kB = 512 * (u + 1) + kl;
            uint4 xwB = *reinterpret_cast<const uint4*>(&xn[kB >> 1]);
            uint4 pB0 = *reinterpret_cast<const uint4*>(pw + 0 * NCF + kB);
            uint4 pB1 = *reinterpret_cast<const uint4*>(pw + 1 * NCF + kB);
            uint4 pB2 = *reinterpret_cast<const uint4*>(pw + 2 * NCF + kB);

            dot_step(xwA, pA0, pA1, pA2, a0, a1, a2);   // compute step u

            if (u + 2 < 16) {                            // prefetch u+2 into A
                const int kA = 512 * (u + 2) + kl;
                xwA = *reinterpret_cast<const uint4*>(&xn[kA >> 1]);
                pA0 = *reinterpret_cast<const uint4*>(pw + 0 * NCF + kA);
                pA1 = *reinterpret_cast<const uint4*>(pw + 1 * NCF + kA);
                pA2 = *reinterpret_cast<const uint4*>(pw + 2 * NCF + kA);
            }

            dot_step(xwB, pB0, pB1, pB2, a0, a1, a2);   // compute step u+1
        }
    }
    {
        float v0 = a0, v1 = a1, v2 = a2;
        #pragma unroll
        for (int m = 1; m < 64; m <<= 1) {
            v0 += __shfl_xor(v0, m, 64);
            v1 += __shfl_xor(v1, m, 64);
            v2 += __shfl_xor(v2, m, 64);
        }
        if (lane == 0) { hred[wave][0] = v0; hred[wave][1] = v1; hred[wave][2] = v2; }
    }
    __syncthreads();

    // ---- finalize h (gather + biases) ----
    if (t < 24) {
        float v = hred[t / 3][t % 3];
        float bias;
        if (t < 4)      bias = b_pre[t];
        else if (t < 8) bias = b_post[t - 4];
        else            bias = b_res[t - 8];
        H[t] = v + bias;
    }
    __syncthreads();

    // ---- Sinkhorn on 4x4 logits, lanes 0..15 ----
    if (t < 16) {
        const int q = t;          // q = i*4 + jx
        float L = H[8 + q];
        float mx = L;
        mx = fmaxf(mx, __shfl_xor(mx, 1, 64));
        mx = fmaxf(mx, __shfl_xor(mx, 2, 64));
        mx = fmaxf(mx, __shfl_xor(mx, 4, 64));
        mx = fmaxf(mx, __shfl_xor(mx, 8, 64));
        float m = __expf(L - mx);
        #pragma unroll
        for (int it = 0; it < SINK_ITERS; ++it) {
            float rs = m + __shfl_xor(m, 1, 64);
            rs += __shfl_xor(rs, 2, 64);
            m = m / (rs + EPS_F);           // row normalize (sum over jx)
            float cs = m + __shfl_xor(m, 4, 64);
            cs += __shfl_xor(cs, 8, 64);
            m = m / (cs + EPS_F);           // col normalize (sum over i)
        }
        H[8 + q] = m;
    }
    __syncthreads();

    // ---- Phase D: mixing epilogue from register-held raw x (exact f32) ----
    {
        float hp[4], hq[4], hrm[4][4];
        #pragma unroll
        for (int i = 0; i < 4; ++i) {
            hp[i] = H[i];
            hq[i] = H[4 + i];
            #pragma unroll
            for (int j = 0; j < 4; ++j) hrm[i][j] = H[8 + 4 * i + j];
        }
        float4 s0 = xv[0], s1 = xv[1], s2 = xv[2], s3 = xv[3];
        float ax = hp[0] * s0.x + hp[1] * s1.x + hp[2] * s2.x + hp[3] * s3.x;
        float ay = hp[0] * s0.y + hp[1] * s1.y + hp[2] * s2.y + hp[3] * s3.y;
        float az = hp[0] * s0.z + hp[1] * s1.z + hp[2] * s2.z + hp[3] * s3.z;
        float aw = hp[0] * s0.w + hp[1] * s1.w + hp[2] * s2.w + hp[3] * s3.w;
        v4f* op = reinterpret_cast<v4f*>(out + b * NCF + 4 * t);
        #pragma unroll
        for (int i = 0; i < 4; ++i) {
            v4f o;
            o.x = hrm[i][0] * s0.x + hrm[i][1] * s1.x + hrm[i][2] * s2.x + hrm[i][3] * s3.x + hq[i] * ax;
            o.y = hrm[i][0] * s0.y + hrm[i][1] * s1.y + hrm[i][2] * s2.y + hrm[i][3] * s3.y + hq[i] * ay;
            o.z = hrm[i][0] * s0.z + hrm[i][1] * s1.z + hrm[i][2] * s2.z + hrm[i][3] * s3.z + hq[i] * az;
            o.w = hrm[i][0] * s0.w + hrm[i][1] * s1.w + hrm[i][2] * s2.w + hrm[i][3] * s3.w + hq[i] * aw;
            __builtin_nontemporal_store(o, op + i * 512);
        }
    }
}

extern "C" void kernel_launch(void* const* d_in, const int* in_sizes, int n_in,
                              void* d_out, int out_size, void* d_ws, size_t ws_size,
                              hipStream_t stream)
{
    const float* x        = (const float*)d_in[0];
    const float* w        = (const float*)d_in[1];
    const float* phi_pre  = (const float*)d_in[2];
    const float* phi_post = (const float*)d_in[3];
    const float* phi_res  = (const float*)d_in[4];
    const float* b_pre    = (const float*)d_in[5];
    const float* b_post   = (const float*)d_in[6];
    const float* b_res    = (const float*)d_in[7];
    const float* a_pre    = (const float*)d_in[8];
    const float* a_post   = (const float*)d_in[9];
    const float* a_res    = (const float*)d_in[10];
    float* out = (float*)d_out;
    uint16_t* phiW = (uint16_t*)d_ws;   // NJ * NCF * 2 bytes = 384 KiB

    const int B = in_sizes[0] / NCF;    // 8192

    prep_phi_kernel<<<(NJ * NCF + 255) / 256, 256, 0, stream>>>(
        w, phi_pre, phi_post, phi_res, a_pre, a_post, a_res, phiW);

    mhc_main_kernel<<<B, 512, 0, stream>>>(
        x, phiW, b_pre, b_post, b_res, out);
}

// Round 7
// 182.675 us; speedup vs baseline: 3.6428x; 1.0983x over previous
//
#include <hip/hip_runtime.h>
#include <hip/hip_bf16.h>
#include <cstdint>

#define CH 2048
#define NCF 8192          // 4 * CH
#define NJ 24             // 4 pre + 4 post + 16 res
#define EPS_F 1e-5f
#define SINK_ITERS 20

typedef float v4f __attribute__((ext_vector_type(4)));

__device__ __forceinline__ uint32_t bf16rne(float f) {
    uint32_t u = __float_as_uint(f);
    return (u + 0x7fffu + ((u >> 16) & 1u)) >> 16;
}

// dot of 8 bf16 pairs (packed in uint4) via v_dot2_f32_bf16
__device__ __forceinline__ float dot8(const uint4& x, const uint4& p, float acc) {
    asm("v_dot2_f32_bf16 %0, %1, %2, %0" : "+v"(acc) : "v"(x.x), "v"(p.x));
    asm("v_dot2_f32_bf16 %0, %1, %2, %0" : "+v"(acc) : "v"(x.y), "v"(p.y));
    asm("v_dot2_f32_bf16 %0, %1, %2, %0" : "+v"(acc) : "v"(x.z), "v"(p.z));
    asm("v_dot2_f32_bf16 %0, %1, %2, %0" : "+v"(acc) : "v"(x.w), "v"(p.w));
    return acc;
}

// ---------------------------------------------------------------------------
// Prep: phiW[j][k] = bf16( alpha_j * w[k % CH] * phi_j[k] ),  j in [0,24)
// ---------------------------------------------------------------------------
__global__ void __launch_bounds__(256) prep_phi_kernel(
    const float* __restrict__ w,
    const float* __restrict__ phi_pre,
    const float* __restrict__ phi_post,
    const float* __restrict__ phi_res,
    const float* __restrict__ alpha_pre,
    const float* __restrict__ alpha_post,
    const float* __restrict__ alpha_res,
    uint16_t* __restrict__ phiW)
{
    int idx = blockIdx.x * 256 + threadIdx.x;
    if (idx >= NJ * NCF) return;
    int j = idx / NCF;
    int k = idx - j * NCF;
    int c = k & (CH - 1);
    float v, a;
    if (j < 4)      { v = phi_pre[j * NCF + k];        a = alpha_pre[0]; }
    else if (j < 8) { v = phi_post[(j - 4) * NCF + k]; a = alpha_post[0]; }
    else            { v = phi_res[(j - 8) * NCF + k];  a = alpha_res[0]; }
    phiW[idx] = (uint16_t)bf16rne(v * a * w[c]);
}

// ---------------------------------------------------------------------------
// Main fused kernel: 512 threads (8 waves), ONE batch row per block.
// x held in registers end-to-end; LDS holds pre-scaled bf16 xnorm (16 KiB).
// Wave w computes projection rows j = 3w..3w+2 via v_dot2_f32_bf16 with a
// 2-stage ping-pong prefetch. Sinkhorn computed redundantly by all lanes
// (16-lane groups), results broadcast in-register. 3 barriers total.
// ---------------------------------------------------------------------------
__global__ void __launch_bounds__(512) mhc_main_kernel(
    const float* __restrict__ x,
    const uint16_t* __restrict__ phiW,
    const float* __restrict__ b_pre,
    const float* __restrict__ b_post,
    const float* __restrict__ b_res,
    float* __restrict__ out)
{
    const int t = threadIdx.x;
    const int lane = t & 63;
    const int wave = t >> 6;              // 0..7
    const long b = blockIdx.x;

    __shared__ uint32_t xn[NCF / 2];      // scaled bf16 xnorm, 16 KiB
    __shared__ float4 red4[8];
    __shared__ float H[24];

    // ---- Phase A: global -> registers, sum-of-squares per stream ----
    float4 xv[4];                          // raw x, quad jj = stream jj
    {
        const float4* xp = reinterpret_cast<const float4*>(x + b * NCF);
        float s0, s1, s2, s3;
        xv[0] = xp[t];
        xv[1] = xp[t + 512];
        xv[2] = xp[t + 1024];
        xv[3] = xp[t + 1536];
        s0 = xv[0].x * xv[0].x + xv[0].y * xv[0].y + xv[0].z * xv[0].z + xv[0].w * xv[0].w;
        s1 = xv[1].x * xv[1].x + xv[1].y * xv[1].y + xv[1].z * xv[1].z + xv[1].w * xv[1].w;
        s2 = xv[2].x * xv[2].x + xv[2].y * xv[2].y + xv[2].z * xv[2].z + xv[2].w * xv[2].w;
        s3 = xv[3].x * xv[3].x + xv[3].y * xv[3].y + xv[3].z * xv[3].z + xv[3].w * xv[3].w;
        #pragma unroll
        for (int m = 1; m < 64; m <<= 1) {
            s0 += __shfl_xor(s0, m, 64);
            s1 += __shfl_xor(s1, m, 64);
            s2 += __shfl_xor(s2, m, 64);
            s3 += __shfl_xor(s3, m, 64);
        }
        if (lane == 0) red4[wave] = make_float4(s0, s1, s2, s3);
    }
    __syncthreads();

    // ---- SCL computed redundantly per thread (broadcast LDS reads) ----
    float scl[4];
    {
        float sx = 0.f, sy = 0.f, sz = 0.f, sw = 0.f;
        #pragma unroll
        for (int w8 = 0; w8 < 8; ++w8) {
            float4 r = red4[w8];
            sx += r.x; sy += r.y; sz += r.z; sw += r.w;
        }
        scl[0] = rsqrtf(sx * (1.0f / CH) + EPS_F);
        scl[1] = rsqrtf(sy * (1.0f / CH) + EPS_F);
        scl[2] = rsqrtf(sz * (1.0f / CH) + EPS_F);
        scl[3] = rsqrtf(sw * (1.0f / CH) + EPS_F);
    }

    // ---- write scaled bf16 xnorm to LDS (packed) ----
    #pragma unroll
    for (int jj = 0; jj < 4; ++jj) {
        const float s = scl[jj];
        uint32_t r0 = bf16rne(xv[jj].x * s);
        uint32_t r1 = bf16rne(xv[jj].y * s);
        uint32_t r2 = bf16rne(xv[jj].z * s);
        uint32_t r3 = bf16rne(xv[jj].w * s);
        uint2 pk = make_uint2(r0 | (r1 << 16), r2 | (r3 << 16));
        *reinterpret_cast<uint2*>(&xn[2 * t + 1024 * jj]) = pk;
    }
    __syncthreads();

    // ---- Phase B: wave w dots xnorm against phi rows 3w..3w+2 ----
    // 16 steps of 512 elems; lane covers 8 elems/step. 2-stage ping-pong.
    float a0 = 0.f, a1 = 0.f, a2 = 0.f;
    {
        const uint16_t* pw = phiW + (size_t)(wave * 3) * NCF;
        const uint4* xnp = reinterpret_cast<const uint4*>(xn);
        const int kl = 8 * lane;

        uint4 xwA = xnp[lane];
        uint4 pA0 = *reinterpret_cast<const uint4*>(pw + 0 * NCF + kl);
        uint4 pA1 = *reinterpret_cast<const uint4*>(pw + 1 * NCF + kl);
        uint4 pA2 = *reinterpret_cast<const uint4*>(pw + 2 * NCF + kl);

        #pragma unroll
        for (int u = 0; u < 16; u += 2) {
            const int kB = 512 * (u + 1) + kl;
            uint4 xwB = xnp[64 * (u + 1) + lane];
            uint4 pB0 = *reinterpret_cast<const uint4*>(pw + 0 * NCF + kB);
            uint4 pB1 = *reinterpret_cast<const uint4*>(pw + 1 * NCF + kB);
            uint4 pB2 = *reinterpret_cast<const uint4*>(pw + 2 * NCF + kB);

            a0 = dot8(xwA, pA0, a0);
            a1 = dot8(xwA, pA1, a1);
            a2 = dot8(xwA, pA2, a2);

            if (u + 2 < 16) {
                const int kA = 512 * (u + 2) + kl;
                xwA = xnp[64 * (u + 2) + lane];
                pA0 = *reinterpret_cast<const uint4*>(pw + 0 * NCF + kA);
                pA1 = *reinterpret_cast<const uint4*>(pw + 1 * NCF + kA);
                pA2 = *reinterpret_cast<const uint4*>(pw + 2 * NCF + kA);
            }

            a0 = dot8(xwB, pB0, a0);
            a1 = dot8(xwB, pB1, a1);
            a2 = dot8(xwB, pB2, a2);
        }
    }
    {
        #pragma unroll
        for (int m = 1; m < 64; m <<= 1) {
            a0 += __shfl_xor(a0, m, 64);
            a1 += __shfl_xor(a1, m, 64);
            a2 += __shfl_xor(a2, m, 64);
        }
        if (lane == 0) {                 // fold bias, write H directly
            float vv[3] = {a0, a1, a2};
            #pragma unroll
            for (int jl = 0; jl < 3; ++jl) {
                int j = 3 * wave + jl;
                float bias;
                if (j < 4)      bias = b_pre[j];
                else if (j < 8) bias = b_post[j - 4];
                else            bias = b_res[j - 8];
                H[j] = vv[jl] + bias;
            }
        }
    }
    __syncthreads();

    // ---- Sinkhorn on 4x4 logits: ALL lanes, 16-lane groups (q = lane&15) --
    float hrm[4][4];
    {
        const int q = lane & 15;          // q = i*4 + jx
        const int g = lane & 48;          // group base within wave
        float L = H[8 + q];
        float mx = L;
        mx = fmaxf(mx, __shfl_xor(mx, 1, 64));
        mx = fmaxf(mx, __shfl_xor(mx, 2, 64));
        mx = fmaxf(mx, __shfl_xor(mx, 4, 64));
        mx = fmaxf(mx, __shfl_xor(mx, 8, 64));
        float m = __expf(L - mx);
        #pragma unroll
        for (int it = 0; it < SINK_ITERS; ++it) {
            float rs = m + __shfl_xor(m, 1, 64);
            rs += __shfl_xor(rs, 2, 64);
            m = m * __builtin_amdgcn_rcpf(rs + EPS_F);   // row normalize
            float cs = m + __shfl_xor(m, 4, 64);
            cs += __shfl_xor(cs, 8, 64);
            m = m * __builtin_amdgcn_rcpf(cs + EPS_F);   // col normalize
        }
        #pragma unroll
        for (int i = 0; i < 4; ++i)
            #pragma unroll
            for (int j = 0; j < 4; ++j)
                hrm[i][j] = __shfl(m, g + 4 * i + j, 64);
    }

    // ---- Phase D: mixing epilogue from register-held raw x (exact f32) ----
    {
        float hp[4], hq[4];
        #pragma unroll
        for (int i = 0; i < 4; ++i) { hp[i] = H[i]; hq[i] = H[4 + i]; }
        float4 s0 = xv[0], s1 = xv[1], s2 = xv[2], s3 = xv[3];
        float ax = hp[0] * s0.x + hp[1] * s1.x + hp[2] * s2.x + hp[3] * s3.x;
        float ay = hp[0] * s0.y + hp[1] * s1.y + hp[2] * s2.y + hp[3] * s3.y;
        float az = hp[0] * s0.z + hp[1] * s1.z + hp[2] * s2.z + hp[3] * s3.z;
        float aw = hp[0] * s0.w + hp[1] * s1.w + hp[2] * s2.w + hp[3] * s3.w;
        v4f* op = reinterpret_cast<v4f*>(out + b * NCF + 4 * t);
        #pragma unroll
        for (int i = 0; i < 4; ++i) {
            v4f o;
            o.x = hrm[i][0] * s0.x + hrm[i][1] * s1.x + hrm[i][2] * s2.x + hrm[i][3] * s3.x + hq[i] * ax;
            o.y = hrm[i][0] * s0.y + hrm[i][1] * s1.y + hrm[i][2] * s2.y + hrm[i][3] * s3.y + hq[i] * ay;
            o.z = hrm[i][0] * s0.z + hrm[i][1] * s1.z + hrm[i][2] * s2.z + hrm[i][3] * s3.z + hq[i] * az;
            o.w = hrm[i][0] * s0.w + hrm[i][1] * s1.w + hrm[i][2] * s2.w + hrm[i][3] * s3.w + hq[i] * aw;
            __builtin_nontemporal_store(o, op + i * 512);
        }
    }
}

extern "C" void kernel_launch(void* const* d_in, const int* in_sizes, int n_in,
                              void* d_out, int out_size, void* d_ws, size_t ws_size,
                              hipStream_t stream)
{
    const float* x        = (const float*)d_in[0];
    const float* w        = (const float*)d_in[1];
    const float* phi_pre  = (const float*)d_in[2];
    const float* phi_post = (const float*)d_in[3];
    const float* phi_res  = (const float*)d_in[4];
    const float* b_pre    = (const float*)d_in[5];
    const float* b_post   = (const float*)d_in[6];
    const float* b_res    = (const float*)d_in[7];
    const float* a_pre    = (const float*)d_in[8];
    const float* a_post   = (const float*)d_in[9];
    const float* a_res    = (const float*)d_in[10];
    float* out = (float*)d_out;
    uint16_t* phiW = (uint16_t*)d_ws;   // NJ * NCF * 2 bytes = 384 KiB

    const int B = in_sizes[0] / NCF;    // 8192

    prep_phi_kernel<<<(NJ * NCF + 255) / 256, 256, 0, stream>>>(
        w, phi_pre, phi_post, phi_res, a_pre, a_post, a_res, phiW);

    mhc_main_kernel<<<B, 512, 0, stream>>>(
        x, phiW, b_pre, b_post, b_res, out);
}

// Round 8
// 171.617 us; speedup vs baseline: 3.8775x; 1.0644x over previous
//
#include <hip/hip_runtime.h>
#include <hip/hip_bf16.h>
#include <cstdint>

#define CH 2048
#define NCF 8192          // 4 * CH
#define NJ 24             // 4 pre + 4 post + 16 res
#define EPS_F 1e-5f
#define SINK_ITERS 20

typedef float v4f __attribute__((ext_vector_type(4)));

__device__ __forceinline__ uint32_t bf16rne(float f) {
    uint32_t u = __float_as_uint(f);
    return (u + 0x7fffu + ((u >> 16) & 1u)) >> 16;
}

// dot of 8 bf16 pairs (packed in uint4) via v_dot2_f32_bf16
__device__ __forceinline__ float dot8(const uint4& x, const uint4& p, float acc) {
    asm("v_dot2_f32_bf16 %0, %1, %2, %0" : "+v"(acc) : "v"(x.x), "v"(p.x));
    asm("v_dot2_f32_bf16 %0, %1, %2, %0" : "+v"(acc) : "v"(x.y), "v"(p.y));
    asm("v_dot2_f32_bf16 %0, %1, %2, %0" : "+v"(acc) : "v"(x.z), "v"(p.z));
    asm("v_dot2_f32_bf16 %0, %1, %2, %0" : "+v"(acc) : "v"(x.w), "v"(p.w));
    return acc;
}

// ---------------------------------------------------------------------------
// Prep: phiW[j][k] = bf16( alpha_j * w[k % CH] * phi_j[k] ),  j in [0,24)
// ---------------------------------------------------------------------------
__global__ void __launch_bounds__(256) prep_phi_kernel(
    const float* __restrict__ w,
    const float* __restrict__ phi_pre,
    const float* __restrict__ phi_post,
    const float* __restrict__ phi_res,
    const float* __restrict__ alpha_pre,
    const float* __restrict__ alpha_post,
    const float* __restrict__ alpha_res,
    uint16_t* __restrict__ phiW)
{
    int idx = blockIdx.x * 256 + threadIdx.x;
    if (idx >= NJ * NCF) return;
    int j = idx / NCF;
    int k = idx - j * NCF;
    int c = k & (CH - 1);
    float v, a;
    if (j < 4)      { v = phi_pre[j * NCF + k];        a = alpha_pre[0]; }
    else if (j < 8) { v = phi_post[(j - 4) * NCF + k]; a = alpha_post[0]; }
    else            { v = phi_res[(j - 8) * NCF + k];  a = alpha_res[0]; }
    phiW[idx] = (uint16_t)bf16rne(v * a * w[c]);
}

// ---------------------------------------------------------------------------
// Main fused kernel: 512 threads (8 waves), TWO batch rows per block.
// Both x rows held in registers end-to-end; LDS holds scaled bf16 xnorm for
// both rows (32 KiB). Each phi load feeds both rows (24 dot-instrs per
// 5 loads). Wave w computes projection rows 3w..3w+2 via v_dot2_f32_bf16
// with ping-pong phi prefetch. Sinkhorn: lanes 0-31 do row 0, 32-63 row 1.
// ---------------------------------------------------------------------------
__global__ void __launch_bounds__(512) mhc_main_kernel(
    const float* __restrict__ x,
    const uint16_t* __restrict__ phiW,
    const float* __restrict__ b_pre,
    const float* __restrict__ b_post,
    const float* __restrict__ b_res,
    float* __restrict__ out)
{
    const int t = threadIdx.x;
    const int lane = t & 63;
    const int wave = t >> 6;              // 0..7
    const long b0 = (long)blockIdx.x * 2;

    __shared__ uint32_t xn[2][NCF / 2];   // scaled bf16 xnorm, 2 rows, 32 KiB
    __shared__ float4 redA[8], redB[8];
    __shared__ float H[2][24];

    // ---- Phase A: global -> registers (both rows), sum-of-squares ----
    float4 xv[2][4];                       // raw x, quad jj = stream jj
    {
        const float4* xp0 = reinterpret_cast<const float4*>(x + b0 * NCF);
        const float4* xp1 = xp0 + (NCF / 4);
        float sa[4], sb[4];
        #pragma unroll
        for (int jj = 0; jj < 4; ++jj) {
            xv[0][jj] = xp0[t + 512 * jj];
            xv[1][jj] = xp1[t + 512 * jj];
            sa[jj] = xv[0][jj].x * xv[0][jj].x + xv[0][jj].y * xv[0][jj].y
                   + xv[0][jj].z * xv[0][jj].z + xv[0][jj].w * xv[0][jj].w;
            sb[jj] = xv[1][jj].x * xv[1][jj].x + xv[1][jj].y * xv[1][jj].y
                   + xv[1][jj].z * xv[1][jj].z + xv[1][jj].w * xv[1][jj].w;
        }
        #pragma unroll
        for (int m = 1; m < 64; m <<= 1) {
            #pragma unroll
            for (int jj = 0; jj < 4; ++jj) {
                sa[jj] += __shfl_xor(sa[jj], m, 64);
                sb[jj] += __shfl_xor(sb[jj], m, 64);
            }
        }
        if (lane == 0) {
            redA[wave] = make_float4(sa[0], sa[1], sa[2], sa[3]);
            redB[wave] = make_float4(sb[0], sb[1], sb[2], sb[3]);
        }
    }
    __syncthreads();

    // ---- SCL computed redundantly per thread (broadcast LDS reads) ----
    float scl[2][4];
    {
        float ax = 0.f, ay = 0.f, az = 0.f, aw = 0.f;
        float bx = 0.f, by = 0.f, bz = 0.f, bw = 0.f;
        #pragma unroll
        for (int w8 = 0; w8 < 8; ++w8) {
            float4 ra = redA[w8], rb = redB[w8];
            ax += ra.x; ay += ra.y; az += ra.z; aw += ra.w;
            bx += rb.x; by += rb.y; bz += rb.z; bw += rb.w;
        }
        scl[0][0] = rsqrtf(ax * (1.0f / CH) + EPS_F);
        scl[0][1] = rsqrtf(ay * (1.0f / CH) + EPS_F);
        scl[0][2] = rsqrtf(az * (1.0f / CH) + EPS_F);
        scl[0][3] = rsqrtf(aw * (1.0f / CH) + EPS_F);
        scl[1][0] = rsqrtf(bx * (1.0f / CH) + EPS_F);
        scl[1][1] = rsqrtf(by * (1.0f / CH) + EPS_F);
        scl[1][2] = rsqrtf(bz * (1.0f / CH) + EPS_F);
        scl[1][3] = rsqrtf(bw * (1.0f / CH) + EPS_F);
    }

    // ---- write scaled bf16 xnorm to LDS (packed, both rows) ----
    #pragma unroll
    for (int r = 0; r < 2; ++r) {
        #pragma unroll
        for (int jj = 0; jj < 4; ++jj) {
            const float s = scl[r][jj];
            uint32_t r0 = bf16rne(xv[r][jj].x * s);
            uint32_t r1 = bf16rne(xv[r][jj].y * s);
            uint32_t r2 = bf16rne(xv[r][jj].z * s);
            uint32_t r3 = bf16rne(xv[r][jj].w * s);
            uint2 pk = make_uint2(r0 | (r1 << 16), r2 | (r3 << 16));
            *reinterpret_cast<uint2*>(&xn[r][2 * t + 1024 * jj]) = pk;
        }
    }
    __syncthreads();

    // ---- Phase B: wave w dots both xnorm rows against phi rows 3w..3w+2 --
    float a00 = 0.f, a01 = 0.f, a02 = 0.f;   // row 0, j = 3w..3w+2
    float a10 = 0.f, a11 = 0.f, a12 = 0.f;   // row 1
    {
        const uint16_t* pw = phiW + (size_t)(wave * 3) * NCF;
        const uint4* x0p = reinterpret_cast<const uint4*>(xn[0]);
        const uint4* x1p = reinterpret_cast<const uint4*>(xn[1]);
        const int kl = 8 * lane;

        uint4 pA0 = *reinterpret_cast<const uint4*>(pw + 0 * NCF + kl);
        uint4 pA1 = *reinterpret_cast<const uint4*>(pw + 1 * NCF + kl);
        uint4 pA2 = *reinterpret_cast<const uint4*>(pw + 2 * NCF + kl);

        #pragma unroll
        for (int u = 0; u < 16; u += 2) {
            const int kB = 512 * (u + 1) + kl;
            uint4 pB0 = *reinterpret_cast<const uint4*>(pw + 0 * NCF + kB);
            uint4 pB1 = *reinterpret_cast<const uint4*>(pw + 1 * NCF + kB);
            uint4 pB2 = *reinterpret_cast<const uint4*>(pw + 2 * NCF + kB);

            uint4 xa = x0p[64 * u + lane];
            uint4 xb = x1p[64 * u + lane];
            a00 = dot8(xa, pA0, a00);
            a01 = dot8(xa, pA1, a01);
            a02 = dot8(xa, pA2, a02);
            a10 = dot8(xb, pA0, a10);
            a11 = dot8(xb, pA1, a11);
            a12 = dot8(xb, pA2, a12);

            if (u + 2 < 16) {
                const int kA = 512 * (u + 2) + kl;
                pA0 = *reinterpret_cast<const uint4*>(pw + 0 * NCF + kA);
                pA1 = *reinterpret_cast<const uint4*>(pw + 1 * NCF + kA);
                pA2 = *reinterpret_cast<const uint4*>(pw + 2 * NCF + kA);
            }

            xa = x0p[64 * (u + 1) + lane];
            xb = x1p[64 * (u + 1) + lane];
            a00 = dot8(xa, pB0, a00);
            a01 = dot8(xa, pB1, a01);
            a02 = dot8(xa, pB2, a02);
            a10 = dot8(xb, pB0, a10);
            a11 = dot8(xb, pB1, a11);
            a12 = dot8(xb, pB2, a12);
        }
    }
    {
        #pragma unroll
        for (int m = 1; m < 64; m <<= 1) {
            a00 += __shfl_xor(a00, m, 64);
            a01 += __shfl_xor(a01, m, 64);
            a02 += __shfl_xor(a02, m, 64);
            a10 += __shfl_xor(a10, m, 64);
            a11 += __shfl_xor(a11, m, 64);
            a12 += __shfl_xor(a12, m, 64);
        }
        if (lane == 0) {                 // fold bias, write H directly
            float v0[3] = {a00, a01, a02};
            float v1[3] = {a10, a11, a12};
            #pragma unroll
            for (int jl = 0; jl < 3; ++jl) {
                int j = 3 * wave + jl;
                float bias;
                if (j < 4)      bias = b_pre[j];
                else if (j < 8) bias = b_post[j - 4];
                else            bias = b_res[j - 8];
                H[0][j] = v0[jl] + bias;
                H[1][j] = v1[jl] + bias;
            }
        }
    }
    __syncthreads();

    // ---- Sinkhorn: lanes 0-31 do row 0's 4x4, lanes 32-63 row 1's ----
    float msink;
    {
        const int r = lane >> 5;
        const int q = lane & 15;          // q = i*4 + jx
        float L = H[r][8 + q];
        float mx = L;
        mx = fmaxf(mx, __shfl_xor(mx, 1, 64));
        mx = fmaxf(mx, __shfl_xor(mx, 2, 64));
        mx = fmaxf(mx, __shfl_xor(mx, 4, 64));
        mx = fmaxf(mx, __shfl_xor(mx, 8, 64));
        float m = __expf(L - mx);
        #pragma unroll
        for (int it = 0; it < SINK_ITERS; ++it) {
            float rs = m + __shfl_xor(m, 1, 64);
            rs += __shfl_xor(rs, 2, 64);
            m = m * __builtin_amdgcn_rcpf(rs + EPS_F);   // row normalize
            float cs = m + __shfl_xor(m, 4, 64);
            cs += __shfl_xor(cs, 8, 64);
            m = m * __builtin_amdgcn_rcpf(cs + EPS_F);   // col normalize
        }
        msink = m;
    }

    // ---- Phase D: mixing epilogue, one row at a time (exact f32) ----
    #pragma unroll
    for (int r = 0; r < 2; ++r) {
        float hp[4], hq[4], hrm[4][4];
        #pragma unroll
        for (int i = 0; i < 4; ++i) {
            hp[i] = H[r][i];
            hq[i] = H[r][4 + i];
            #pragma unroll
            for (int j = 0; j < 4; ++j)
                hrm[i][j] = __shfl(msink, 32 * r + 4 * i + j, 64);
        }
        float4 s0 = xv[r][0], s1 = xv[r][1], s2 = xv[r][2], s3 = xv[r][3];
        float ax = hp[0] * s0.x + hp[1] * s1.x + hp[2] * s2.x + hp[3] * s3.x;
        float ay = hp[0] * s0.y + hp[1] * s1.y + hp[2] * s2.y + hp[3] * s3.y;
        float az = hp[0] * s0.z + hp[1] * s1.z + hp[2] * s2.z + hp[3] * s3.z;
        float aw = hp[0] * s0.w + hp[1] * s1.w + hp[2] * s2.w + hp[3] * s3.w;
        v4f* op = reinterpret_cast<v4f*>(out + (b0 + r) * NCF + 4 * t);
        #pragma unroll
        for (int i = 0; i < 4; ++i) {
            v4f o;
            o.x = hrm[i][0] * s0.x + hrm[i][1] * s1.x + hrm[i][2] * s2.x + hrm[i][3] * s3.x + hq[i] * ax;
            o.y = hrm[i][0] * s0.y + hrm[i][1] * s1.y + hrm[i][2] * s2.y + hrm[i][3] * s3.y + hq[i] * ay;
            o.z = hrm[i][0] * s0.z + hrm[i][1] * s1.z + hrm[i][2] * s2.z + hrm[i][3] * s3.z + hq[i] * az;
            o.w = hrm[i][0] * s0.w + hrm[i][1] * s1.w + hrm[i][2] * s2.w + hrm[i][3] * s3.w + hq[i] * aw;
            __builtin_nontemporal_store(o, op + i * 512);
        }
    }
}

extern "C" void kernel_launch(void* const* d_in, const int* in_sizes, int n_in,
                              void* d_out, int out_size, void* d_ws, size_t ws_size,
                              hipStream_t stream)
{
    const float* x        = (const float*)d_in[0];
    const float* w        = (const float*)d_in[1];
    const float* phi_pre  = (const float*)d_in[2];
    const float* phi_post = (const float*)d_in[3];
    const float* phi_res  = (const float*)d_in[4];
    const float* b_pre    = (const float*)d_in[5];
    const float* b_post   = (const float*)d_in[6];
    const float* b_res    = (const float*)d_in[7];
    const float* a_pre    = (const float*)d_in[8];
    const float* a_post   = (const float*)d_in[9];
    const float* a_res    = (const float*)d_in[10];
    float* out = (float*)d_out;
    uint16_t* phiW = (uint16_t*)d_ws;   // NJ * NCF * 2 bytes = 384 KiB

    const int B = in_sizes[0] / NCF;    // 8192

    prep_phi_kernel<<<(NJ * NCF + 255) / 256, 256, 0, stream>>>(
        w, phi_pre, phi_post, phi_res, a_pre, a_post, a_res, phiW);

    mhc_main_kernel<<<B / 2, 512, 0, stream>>>(
        x, phiW, b_pre, b_post, b_res, out);
}

// Round 9
// 133.872 us; speedup vs baseline: 4.9707x; 1.2819x over previous
//
#include <hip/hip_runtime.h>
#include <hip/hip_bf16.h>
#include <cstdint>

#define CH 2048
#define NCF 8192          // 4 * CH
#define NJ 24             // 4 pre + 4 post + 16 res
#define RPB 4             // batch rows per block
#define EPS_F 1e-5f
#define SINK_ITERS 20

typedef float v4f __attribute__((ext_vector_type(4)));

__device__ __forceinline__ uint32_t bf16rne(float f) {
    uint32_t u = __float_as_uint(f);
    return (u + 0x7fffu + ((u >> 16) & 1u)) >> 16;
}

// dot of 8 bf16 pairs (packed in uint4) via v_dot2_f32_bf16
__device__ __forceinline__ float dot8(const uint4& x, const uint4& p, float acc) {
    asm("v_dot2_f32_bf16 %0, %1, %2, %0" : "+v"(acc) : "v"(x.x), "v"(p.x));
    asm("v_dot2_f32_bf16 %0, %1, %2, %0" : "+v"(acc) : "v"(x.y), "v"(p.y));
    asm("v_dot2_f32_bf16 %0, %1, %2, %0" : "+v"(acc) : "v"(x.z), "v"(p.z));
    asm("v_dot2_f32_bf16 %0, %1, %2, %0" : "+v"(acc) : "v"(x.w), "v"(p.w));
    return acc;
}

// ---------------------------------------------------------------------------
// Prep: phiW[j][k] = bf16( alpha_j * w[k % CH] * phi_j[k] ),  j in [0,24)
// ---------------------------------------------------------------------------
__global__ void __launch_bounds__(256) prep_phi_kernel(
    const float* __restrict__ w,
    const float* __restrict__ phi_pre,
    const float* __restrict__ phi_post,
    const float* __restrict__ phi_res,
    const float* __restrict__ alpha_pre,
    const float* __restrict__ alpha_post,
    const float* __restrict__ alpha_res,
    uint16_t* __restrict__ phiW)
{
    int idx = blockIdx.x * 256 + threadIdx.x;
    if (idx >= NJ * NCF) return;
    int j = idx / NCF;
    int k = idx - j * NCF;
    int c = k & (CH - 1);
    float v, a;
    if (j < 4)      { v = phi_pre[j * NCF + k];        a = alpha_pre[0]; }
    else if (j < 8) { v = phi_post[(j - 4) * NCF + k]; a = alpha_post[0]; }
    else            { v = phi_res[(j - 8) * NCF + k];  a = alpha_res[0]; }
    phiW[idx] = (uint16_t)bf16rne(v * a * w[c]);
}

// ---------------------------------------------------------------------------
// Main fused kernel: 512 threads (8 waves), FOUR batch rows per block.
// LDS holds RAW bf16 x for all 4 rows (64 KiB). RMS scale is folded into
// the dot accumulation at stream-segment boundaries (accS -> accT), so the
// staging needs no scale and the epilogue mixes from the same raw bf16 x.
// Each phi load feeds 4 rows (48 dot2-instrs per 3 phi + 4 LDS loads).
// Sinkhorn: 4 rows x 16-lane groups = all 64 lanes. 2 barriers total.
// ---------------------------------------------------------------------------
__global__ void __launch_bounds__(512) mhc_main_kernel(
    const float* __restrict__ x,
    const uint16_t* __restrict__ phiW,
    const float* __restrict__ b_pre,
    const float* __restrict__ b_post,
    const float* __restrict__ b_res,
    float* __restrict__ out)
{
    const int t = threadIdx.x;
    const int lane = t & 63;
    const int wave = t >> 6;              // 0..7
    const long b0 = (long)blockIdx.x * RPB;

    __shared__ uint32_t xn[RPB][NCF / 2]; // raw bf16 x, 4 rows, 64 KiB
    __shared__ float4 red[RPB][8];
    __shared__ float H[RPB][24];

    // ---- Phase A: global -> LDS (raw bf16), sum-of-squares per stream ----
    {
        const float4* xp = reinterpret_cast<const float4*>(x + b0 * NCF);
        #pragma unroll
        for (int r = 0; r < RPB; ++r) {
            float ss0, ss1, ss2, ss3;
            {
                float4 a0 = xp[r * 2048 + t];
                float4 a1 = xp[r * 2048 + t + 512];
                float4 a2 = xp[r * 2048 + t + 1024];
                float4 a3 = xp[r * 2048 + t + 1536];
                ss0 = a0.x*a0.x + a0.y*a0.y + a0.z*a0.z + a0.w*a0.w;
                ss1 = a1.x*a1.x + a1.y*a1.y + a1.z*a1.z + a1.w*a1.w;
                ss2 = a2.x*a2.x + a2.y*a2.y + a2.z*a2.z + a2.w*a2.w;
                ss3 = a3.x*a3.x + a3.y*a3.y + a3.z*a3.z + a3.w*a3.w;
                *reinterpret_cast<uint2*>(&xn[r][2*t]) =
                    make_uint2(bf16rne(a0.x) | (bf16rne(a0.y) << 16),
                               bf16rne(a0.z) | (bf16rne(a0.w) << 16));
                *reinterpret_cast<uint2*>(&xn[r][2*t + 1024]) =
                    make_uint2(bf16rne(a1.x) | (bf16rne(a1.y) << 16),
                               bf16rne(a1.z) | (bf16rne(a1.w) << 16));
                *reinterpret_cast<uint2*>(&xn[r][2*t + 2048]) =
                    make_uint2(bf16rne(a2.x) | (bf16rne(a2.y) << 16),
                               bf16rne(a2.z) | (bf16rne(a2.w) << 16));
                *reinterpret_cast<uint2*>(&xn[r][2*t + 3072]) =
                    make_uint2(bf16rne(a3.x) | (bf16rne(a3.y) << 16),
                               bf16rne(a3.z) | (bf16rne(a3.w) << 16));
            }
            #pragma unroll
            for (int m = 1; m < 64; m <<= 1) {
                ss0 += __shfl_xor(ss0, m, 64);
                ss1 += __shfl_xor(ss1, m, 64);
                ss2 += __shfl_xor(ss2, m, 64);
                ss3 += __shfl_xor(ss3, m, 64);
            }
            if (lane == 0) red[r][wave] = make_float4(ss0, ss1, ss2, ss3);
        }
    }
    __syncthreads();

    // ---- SCL computed redundantly per thread (broadcast LDS reads) ----
    float scl[RPB][4];
    #pragma unroll
    for (int r = 0; r < RPB; ++r) {
        float sx = 0.f, sy = 0.f, sz = 0.f, sw = 0.f;
        #pragma unroll
        for (int w8 = 0; w8 < 8; ++w8) {
            float4 v = red[r][w8];
            sx += v.x; sy += v.y; sz += v.z; sw += v.w;
        }
        scl[r][0] = rsqrtf(sx * (1.0f / CH) + EPS_F);
        scl[r][1] = rsqrtf(sy * (1.0f / CH) + EPS_F);
        scl[r][2] = rsqrtf(sz * (1.0f / CH) + EPS_F);
        scl[r][3] = rsqrtf(sw * (1.0f / CH) + EPS_F);
    }

    // ---- Phase B: wave w dots 4 raw rows against phi rows 3w..3w+2 ----
    // 16 steps of 512 elems; scl folded at the 4 stream boundaries.
    float accT[3][RPB] = {};
    float accS[3][RPB] = {};
    {
        const uint16_t* pw = phiW + (size_t)(wave * 3) * NCF;
        const int kl = 8 * lane;
        const uint4* xr0 = reinterpret_cast<const uint4*>(xn[0]);
        const uint4* xr1 = reinterpret_cast<const uint4*>(xn[1]);
        const uint4* xr2 = reinterpret_cast<const uint4*>(xn[2]);
        const uint4* xr3 = reinterpret_cast<const uint4*>(xn[3]);

        uint4 pA0 = *reinterpret_cast<const uint4*>(pw + 0 * NCF + kl);
        uint4 pA1 = *reinterpret_cast<const uint4*>(pw + 1 * NCF + kl);
        uint4 pA2 = *reinterpret_cast<const uint4*>(pw + 2 * NCF + kl);
        uint4 xA0 = xr0[lane], xA1 = xr1[lane], xA2 = xr2[lane], xA3 = xr3[lane];

        #pragma unroll
        for (int u = 0; u < 16; u += 2) {
            const int iB = 64 * (u + 1) + lane;
            const int kB = 512 * (u + 1) + kl;
            uint4 pB0 = *reinterpret_cast<const uint4*>(pw + 0 * NCF + kB);
            uint4 pB1 = *reinterpret_cast<const uint4*>(pw + 1 * NCF + kB);
            uint4 pB2 = *reinterpret_cast<const uint4*>(pw + 2 * NCF + kB);
            uint4 xB0 = xr0[iB], xB1 = xr1[iB], xB2 = xr2[iB], xB3 = xr3[iB];

            accS[0][0] = dot8(xA0, pA0, accS[0][0]);
            accS[0][1] = dot8(xA1, pA0, accS[0][1]);
            accS[0][2] = dot8(xA2, pA0, accS[0][2]);
            accS[0][3] = dot8(xA3, pA0, accS[0][3]);
            accS[1][0] = dot8(xA0, pA1, accS[1][0]);
            accS[1][1] = dot8(xA1, pA1, accS[1][1]);
            accS[1][2] = dot8(xA2, pA1, accS[1][2]);
            accS[1][3] = dot8(xA3, pA1, accS[1][3]);
            accS[2][0] = dot8(xA0, pA2, accS[2][0]);
            accS[2][1] = dot8(xA1, pA2, accS[2][1]);
            accS[2][2] = dot8(xA2, pA2, accS[2][2]);
            accS[2][3] = dot8(xA3, pA2, accS[2][3]);

            if (u + 2 < 16) {
                const int iA = 64 * (u + 2) + lane;
                const int kA = 512 * (u + 2) + kl;
                pA0 = *reinterpret_cast<const uint4*>(pw + 0 * NCF + kA);
                pA1 = *reinterpret_cast<const uint4*>(pw + 1 * NCF + kA);
                pA2 = *reinterpret_cast<const uint4*>(pw + 2 * NCF + kA);
                xA0 = xr0[iA]; xA1 = xr1[iA]; xA2 = xr2[iA]; xA3 = xr3[iA];
            }

            accS[0][0] = dot8(xB0, pB0, accS[0][0]);
            accS[0][1] = dot8(xB1, pB0, accS[0][1]);
            accS[0][2] = dot8(xB2, pB0, accS[0][2]);
            accS[0][3] = dot8(xB3, pB0, accS[0][3]);
            accS[1][0] = dot8(xB0, pB1, accS[1][0]);
            accS[1][1] = dot8(xB1, pB1, accS[1][1]);
            accS[1][2] = dot8(xB2, pB1, accS[1][2]);
            accS[1][3] = dot8(xB3, pB1, accS[1][3]);
            accS[2][0] = dot8(xB0, pB2, accS[2][0]);
            accS[2][1] = dot8(xB1, pB2, accS[2][1]);
            accS[2][2] = dot8(xB2, pB2, accS[2][2]);
            accS[2][3] = dot8(xB3, pB2, accS[2][3]);

            if (((u + 1) & 3) == 3) {               // end of stream segment
                const int s = (u + 1) >> 2;
                #pragma unroll
                for (int jl = 0; jl < 3; ++jl) {
                    #pragma unroll
                    for (int r = 0; r < RPB; ++r) {
                        accT[jl][r] = fmaf(scl[r][s], accS[jl][r], accT[jl][r]);
                        accS[jl][r] = 0.f;
                    }
                }
            }
        }
    }
    {
        #pragma unroll
        for (int m = 1; m < 64; m <<= 1) {
            #pragma unroll
            for (int jl = 0; jl < 3; ++jl) {
                #pragma unroll
                for (int r = 0; r < RPB; ++r)
                    accT[jl][r] += __shfl_xor(accT[jl][r], m, 64);
            }
        }
        if (lane == 0) {                 // fold bias, write H directly
            #pragma unroll
            for (int jl = 0; jl < 3; ++jl) {
                int j = 3 * wave + jl;
                float bias;
                if (j < 4)      bias = b_pre[j];
                else if (j < 8) bias = b_post[j - 4];
                else            bias = b_res[j - 8];
                #pragma unroll
                for (int r = 0; r < RPB; ++r) H[r][j] = accT[jl][r] + bias;
            }
        }
    }
    __syncthreads();

    // ---- Sinkhorn: 16-lane group g handles row g (4 rows = 64 lanes) ----
    float msink;
    {
        const int r = lane >> 4;
        const int q = lane & 15;          // q = i*4 + jx
        float L = H[r][8 + q];
        float mx = L;
        mx = fmaxf(mx, __shfl_xor(mx, 1, 64));
        mx = fmaxf(mx, __shfl_xor(mx, 2, 64));
        mx = fmaxf(mx, __shfl_xor(mx, 4, 64));
        mx = fmaxf(mx, __shfl_xor(mx, 8, 64));
        float m = __expf(L - mx);
        #pragma unroll
        for (int it = 0; it < SINK_ITERS; ++it) {
            float rs = m + __shfl_xor(m, 1, 64);
            rs += __shfl_xor(rs, 2, 64);
            m = m * __builtin_amdgcn_rcpf(rs + EPS_F);   // row normalize
            float cs = m + __shfl_xor(m, 4, 64);
            cs += __shfl_xor(cs, 8, 64);
            m = m * __builtin_amdgcn_rcpf(cs + EPS_F);   // col normalize
        }
        msink = m;
    }

    // ---- Phase D: mixing epilogue from LDS raw bf16 x ----
    #pragma unroll
    for (int r = 0; r < RPB; ++r) {
        float hp[4], hq[4], hrm[4][4];
        #pragma unroll
        for (int i = 0; i < 4; ++i) {
            hp[i] = H[r][i];
            hq[i] = H[r][4 + i];
            #pragma unroll
            for (int j = 0; j < 4; ++j)
                hrm[i][j] = __shfl(msink, 16 * r + 4 * i + j, 64);
        }
        float4 s[4];
        #pragma unroll
        for (int jj = 0; jj < 4; ++jj) {
            uint2 pk = *reinterpret_cast<const uint2*>(&xn[r][2 * t + 1024 * jj]);
            s[jj].x = __uint_as_float(pk.x << 16);
            s[jj].y = __uint_as_float(pk.x & 0xffff0000u);
            s[jj].z = __uint_as_float(pk.y << 16);
            s[jj].w = __uint_as_float(pk.y & 0xffff0000u);
        }
        float ax = hp[0]*s[0].x + hp[1]*s[1].x + hp[2]*s[2].x + hp[3]*s[3].x;
        float ay = hp[0]*s[0].y + hp[1]*s[1].y + hp[2]*s[2].y + hp[3]*s[3].y;
        float az = hp[0]*s[0].z + hp[1]*s[1].z + hp[2]*s[2].z + hp[3]*s[3].z;
        float aw = hp[0]*s[0].w + hp[1]*s[1].w + hp[2]*s[2].w + hp[3]*s[3].w;
        v4f* op = reinterpret_cast<v4f*>(out + (b0 + r) * NCF + 4 * t);
        #pragma unroll
        for (int i = 0; i < 4; ++i) {
            v4f o;
            o.x = hrm[i][0]*s[0].x + hrm[i][1]*s[1].x + hrm[i][2]*s[2].x + hrm[i][3]*s[3].x + hq[i]*ax;
            o.y = hrm[i][0]*s[0].y + hrm[i][1]*s[1].y + hrm[i][2]*s[2].y + hrm[i][3]*s[3].y + hq[i]*ay;
            o.z = hrm[i][0]*s[0].z + hrm[i][1]*s[1].z + hrm[i][2]*s[2].z + hrm[i][3]*s[3].z + hq[i]*az;
            o.w = hrm[i][0]*s[0].w + hrm[i][1]*s[1].w + hrm[i][2]*s[2].w + hrm[i][3]*s[3].w + hq[i]*aw;
            __builtin_nontemporal_store(o, op + i * 512);
        }
    }
}

extern "C" void kernel_launch(void* const* d_in, const int* in_sizes, int n_in,
                              void* d_out, int out_size, void* d_ws, size_t ws_size,
                              hipStream_t stream)
{
    const float* x        = (const float*)d_in[0];
    const float* w        = (const float*)d_in[1];
    const float* phi_pre  = (const float*)d_in[2];
    const float* phi_post = (const float*)d_in[3];
    const float* phi_res  = (const float*)d_in[4];
    const float* b_pre    = (const float*)d_in[5];
    const float* b_post   = (const float*)d_in[6];
    const float* b_res    = (const float*)d_in[7];
    const float* a_pre    = (const float*)d_in[8];
    const float* a_post   = (const float*)d_in[9];
    const float* a_res    = (const float*)d_in[10];
    float* out = (float*)d_out;
    uint16_t* phiW = (uint16_t*)d_ws;   // NJ * NCF * 2 bytes = 384 KiB

    const int B = in_sizes[0] / NCF;    // 8192

    prep_phi_kernel<<<(NJ * NCF + 255) / 256, 256, 0, stream>>>(
        w, phi_pre, phi_post, phi_res, a_pre, a_post, a_res, phiW);

    mhc_main_kernel<<<B / RPB, 512, 0, stream>>>(
        x, phiW, b_pre, b_post, b_res, out);
}